// Round 1
// 2722.663 us; speedup vs baseline: 1.0105x; 1.0105x over previous
//
#include <hip/hip_runtime.h>
#include <cstdint>
#include <cstddef>

// SpatialAttention fused pipeline, fp32 (round 2).
//
// Restructure vs round 1: swap GEMM order using linearity of the w_e conv:
//   E0[b,c,h,w] = Sum_k S[b,h,k] * D[b,c,k,w],  D = lrelu(w_fd @ F)   (k_smm)
//   out[b,o,p]  = Sum_c w_e[o,c] * E0[b,c,p] + x[b,o,p]   in-place    (k_emm)
// This removes the 419MB G read that made k_out_f latency-bound (8.6% HBM,
// 23.8% VALU, 12% occ): k_smm's inputs (S 102KB/b, F 410KB/b) are L2-hot.
// E0 lives in d_out; k_emm is in-place per 64-pixel column (reads all 256 c
// before writing all 256 o -> no cross-block hazard).
// Workspace: 14.75 MB (w_eT reuses the avg slot, dead after k_convs).

#define SLOPE 0.001f
#define B_    16
#define C_    256
#define H_    160
#define W_    160
#define HW_   25600
#define NPIX_ 409600

__device__ __forceinline__ float lrelu(float v) { return v > 0.f ? v : SLOPE * v; }

// ---------------------------------------------------------------------------
// K1: per-pixel channel reduction: avg, max, Bm = lrelu(w_ab . x)
// grid 1600 x 64 threads, each thread one float4 (4 pixels). 419MB read.
// ---------------------------------------------------------------------------
__global__ void k_reduce(const float* __restrict__ x, const float* __restrict__ w_ab,
                         float* __restrict__ avg, float* __restrict__ mx,
                         float* __restrict__ bm) {
  int idx = blockIdx.x * 64 + threadIdx.x;          // 0 .. NPIX_/4-1
  int b   = idx / (HW_ / 4);
  int p4  = idx - b * (HW_ / 4);
  const float4* xb = (const float4*)x + (size_t)b * C_ * (HW_ / 4) + p4;
  float4 s = make_float4(0.f, 0.f, 0.f, 0.f);
  float4 m = make_float4(-INFINITY, -INFINITY, -INFINITY, -INFINITY);
  float4 d = make_float4(0.f, 0.f, 0.f, 0.f);
#pragma unroll 4
  for (int c = 0; c < C_; ++c) {
    float4 v = xb[(size_t)c * (HW_ / 4)];
    float  wc = w_ab[c];
    s.x += v.x; s.y += v.y; s.z += v.z; s.w += v.w;
    m.x = fmaxf(m.x, v.x); m.y = fmaxf(m.y, v.y);
    m.z = fmaxf(m.z, v.z); m.w = fmaxf(m.w, v.w);
    d.x = fmaf(wc, v.x, d.x); d.y = fmaf(wc, v.y, d.y);
    d.z = fmaf(wc, v.z, d.z); d.w = fmaf(wc, v.w, d.w);
  }
  int o4 = b * (HW_ / 4) + p4;
  const float inv = 1.f / (float)C_;
  ((float4*)avg)[o4] = make_float4(s.x * inv, s.y * inv, s.z * inv, s.w * inv);
  ((float4*)mx)[o4]  = m;
  ((float4*)bm)[o4]  = make_float4(lrelu(d.x), lrelu(d.y), lrelu(d.z), lrelu(d.w));
}

// ---------------------------------------------------------------------------
// K2: S1/S3/S5/S7 convs on AM=(avg,max) + Cm. 16x16 tile + 3-halo in LDS.
// grid (10,10,16) x 256 threads.
// ---------------------------------------------------------------------------
__global__ void k_convs(const float* __restrict__ avg, const float* __restrict__ mx,
                        const float* __restrict__ w1, const float* __restrict__ w3,
                        const float* __restrict__ w5, const float* __restrict__ w7,
                        const float* __restrict__ w_fc,
                        float* __restrict__ F, float* __restrict__ cm) {
  __shared__ float Aa[22][22];
  __shared__ float Am[22][22];
  int b = blockIdx.z, h0 = blockIdx.y * 16, w0 = blockIdx.x * 16;
  int t = threadIdx.x;
  const float* ab = avg + b * HW_;
  const float* mb = mx + b * HW_;
  for (int i = t; i < 22 * 22; i += 256) {
    int ih = i / 22, iw = i - ih * 22;
    int gh = h0 + ih - 3, gw = w0 + iw - 3;
    bool in = ((unsigned)gh < 160u) && ((unsigned)gw < 160u);
    Aa[ih][iw] = in ? ab[gh * 160 + gw] : 0.f;
    Am[ih][iw] = in ? mb[gh * 160 + gw] : 0.f;
  }
  __syncthreads();
  int ty = t >> 4, tx = t & 15;
  float s1 = w1[0] * Aa[ty + 3][tx + 3] + w1[1] * Am[ty + 3][tx + 3];
  float s3 = 0.f, s5 = 0.f, s7 = 0.f;
#pragma unroll
  for (int kh = 0; kh < 3; ++kh)
#pragma unroll
    for (int kw = 0; kw < 3; ++kw)
      s3 += w3[kh * 3 + kw] * Aa[ty + 2 + kh][tx + 2 + kw] +
            w3[9 + kh * 3 + kw] * Am[ty + 2 + kh][tx + 2 + kw];
#pragma unroll
  for (int kh = 0; kh < 5; ++kh)
#pragma unroll
    for (int kw = 0; kw < 5; ++kw)
      s5 += w5[kh * 5 + kw] * Aa[ty + 1 + kh][tx + 1 + kw] +
            w5[25 + kh * 5 + kw] * Am[ty + 1 + kh][tx + 1 + kw];
#pragma unroll
  for (int kh = 0; kh < 7; ++kh)
#pragma unroll
    for (int kw = 0; kw < 7; ++kw)
      s7 += w7[kh * 7 + kw] * Aa[ty + kh][tx + kw] +
            w7[49 + kh * 7 + kw] * Am[ty + kh][tx + kw];
  s1 = lrelu(s1); s3 = lrelu(s3); s5 = lrelu(s5); s7 = lrelu(s7);
  int hw = (h0 + ty) * 160 + (w0 + tx);
  F[(b * 4 + 0) * HW_ + hw] = s1;
  F[(b * 4 + 1) * HW_ + hw] = s3;
  F[(b * 4 + 2) * HW_ + hw] = s5;
  F[(b * 4 + 3) * HW_ + hw] = s7;
  cm[b * HW_ + hw] = lrelu(w_fc[0] * s1 + w_fc[1] * s3 + w_fc[2] * s5 + w_fc[3] * s7);
}

// ---------------------------------------------------------------------------
// K3: logits L[h,k] = Sum_w Bm[b,h,w]*Cm[b,w,k], softmax over k -> S.
// grid (160,16) x 256 threads (160 active).
// ---------------------------------------------------------------------------
__global__ void k_attn(const float* __restrict__ bm, const float* __restrict__ cm,
                       float* __restrict__ S) {
  int h = blockIdx.x, b = blockIdx.y;
  int t = threadIdx.x;
  __shared__ float row[160];
  __shared__ float red[256];
  const float* bmr = bm + b * HW_ + h * 160;
  const float* cmb = cm + b * HW_;
  if (t < 160) row[t] = bmr[t];
  __syncthreads();
  float acc = 0.f;
  if (t < 160) {
    for (int w = 0; w < 160; ++w) acc = fmaf(row[w], cmb[w * 160 + t], acc);
  }
  red[t] = (t < 160) ? acc : -INFINITY;
  __syncthreads();
  for (int s = 128; s > 0; s >>= 1) {
    if (t < s) red[t] = fmaxf(red[t], red[t + s]);
    __syncthreads();
  }
  float mval = red[0];
  __syncthreads();
  float e = (t < 160) ? __expf(acc - mval) : 0.f;
  red[t] = e;
  __syncthreads();
  for (int s = 128; s > 0; s >>= 1) {
    if (t < s) red[t] += red[t + s];
    __syncthreads();
  }
  float inv = 1.f / red[0];
  if (t < 160) S[(b * 160 + h) * 160 + t] = e * inv;
}

// ---------------------------------------------------------------------------
// K_wt: transpose w_e (o,c) -> w_eT (c,o) once, so k_emm's weight loads are
// coalesced rows. 256KB, L2-resident afterwards. grid 256 x 256.
// ---------------------------------------------------------------------------
__global__ void k_wt(const float* __restrict__ w_e, float* __restrict__ w_eT) {
  int c = blockIdx.x;
  int o = threadIdx.x;
  w_eT[c * 256 + o] = w_e[o * 256 + c];
}

// ---------------------------------------------------------------------------
// K4 (k_smm): E0[b,c,h,w] = Sum_k S[b,h,k] * lrelu(w_fd[c] . F[b,:,k,w])
// One block per (c,b): full 160x160 plane, 10x10 per thread (strided 16),
// k-tiles of 16. Inputs S (102KB/b) + F (410KB/b) are L2-hot across the 256
// c-blocks of a batch -> no big global reads. Writes E0 into d_out (419MB).
// LDS 20.5KB: St[160][16] (2-way bcast reads = free), Dt[16][160]
// (consecutive-lane reads = conflict-free). grid (256,16) x 256.
// ---------------------------------------------------------------------------
__global__ __launch_bounds__(256, 3) void k_smm(
    const float* __restrict__ S, const float* __restrict__ F,
    const float* __restrict__ w_fd, float* __restrict__ E0) {
  __shared__ float St[160 * 16];   // [h][kk]
  __shared__ float Dt[16 * 160];   // [kk][w]
  int c = blockIdx.x, b = blockIdx.y;
  int t = threadIdx.x, tx = t & 15, ty = t >> 4;
  float wf[4];
  *(float4*)wf = *(const float4*)(w_fd + c * 4);
  const float* Sb = S + b * HW_;
  const float* Fb = F + (size_t)b * 4 * HW_;
  float acc[10][10];
#pragma unroll
  for (int i = 0; i < 10; ++i)
#pragma unroll
    for (int j = 0; j < 10; ++j) acc[i][j] = 0.f;

  for (int kt = 0; kt < 160; kt += 16) {
    __syncthreads();  // prev tile's LDS reads done
    // S tile: 160 rows x 16 k, coalesced 64B/row, b128 LDS writes
    for (int i = t; i < 640; i += 256) {
      int h = i >> 2, c4 = (i & 3) << 2;
      *(float4*)(St + h * 16 + c4) = *(const float4*)(Sb + h * 160 + kt + c4);
    }
    // D tile from F (4 rows, L2-hot): 16 k x 160 w
    for (int i = t; i < 640; i += 256) {
      int kk = i / 40, w4 = (i - kk * 40) << 2;
      const float* fp = Fb + (kt + kk) * 160 + w4;
      float f0[4], f1[4], f2[4], f3[4], d[4];
      *(float4*)f0 = *(const float4*)(fp);
      *(float4*)f1 = *(const float4*)(fp + HW_);
      *(float4*)f2 = *(const float4*)(fp + 2 * HW_);
      *(float4*)f3 = *(const float4*)(fp + 3 * HW_);
#pragma unroll
      for (int q = 0; q < 4; ++q)
        d[q] = lrelu(wf[0] * f0[q] + wf[1] * f1[q] + wf[2] * f2[q] + wf[3] * f3[q]);
      *(float4*)(Dt + kk * 160 + w4) = *(float4*)d;
    }
    __syncthreads();
#pragma unroll 4
    for (int kk = 0; kk < 16; ++kk) {
      float aR[10], bR[10];
#pragma unroll
      for (int i = 0; i < 10; ++i) aR[i] = St[(ty + 16 * i) * 16 + kk];
#pragma unroll
      for (int j = 0; j < 10; ++j) bR[j] = Dt[kk * 160 + tx + 16 * j];
#pragma unroll
      for (int i = 0; i < 10; ++i)
#pragma unroll
        for (int j = 0; j < 10; ++j) acc[i][j] = fmaf(aR[i], bR[j], acc[i][j]);
    }
  }
  float* Eb = E0 + ((size_t)(b * 256 + c)) * HW_;
#pragma unroll
  for (int i = 0; i < 10; ++i) {
    int h = ty + 16 * i;
#pragma unroll
    for (int j = 0; j < 10; ++j) Eb[h * 160 + tx + 16 * j] = acc[i][j];
  }
}

// ---------------------------------------------------------------------------
// K5 (k_emm): out[b,o,p] = Sum_c w_eT[c,o] * E0[b,c,p] + x[b,o,p], IN PLACE
// on d_out. Block = (b, 64-pixel column): M=256(o) x N=64(p) x K=256, k-tiles
// of 16. All E0 reads of the column complete before any out write (barrier
// after last load phase) -> in-place safe; blocks are pixel-disjoint.
// Per thread 16o x 4p; all LDS fragment traffic is b128, conflict-free.
// LDS 20KB, acc 64 -> ~4 blocks/CU. grid (400,16) x 256.
// ---------------------------------------------------------------------------
__global__ __launch_bounds__(256, 4) void k_emm(
    const float* __restrict__ w_eT, const float* __restrict__ x,
    float* __restrict__ out) {
  __shared__ float Wt[16 * 256];  // [cc][o]
  __shared__ float Et[16 * 64];   // [cc][p]
  int px0 = blockIdx.x * 64, b = blockIdx.y;
  int t = threadIdx.x, tx = t & 15, ty = t >> 4;
  float acc[16][4];
#pragma unroll
  for (int i = 0; i < 16; ++i)
#pragma unroll
    for (int j = 0; j < 4; ++j) acc[i][j] = 0.f;
  const float* Eb = out + (size_t)b * 256 * HW_ + px0;  // E0 lives in d_out

  for (int ct = 0; ct < 256; ct += 16) {
    __syncthreads();  // prev tile's LDS reads done
    // Et: 16 c-rows x 64 pix, one float4/thread, 256B/row coalesced
    *(float4*)(Et + ty * 64 + tx * 4) =
        *(const float4*)(Eb + (size_t)(ct + ty) * HW_ + tx * 4);
    // Wt: 16 c-rows x 256 o from w_eT (L2-resident), coalesced
#pragma unroll
    for (int r = 0; r < 4; ++r) {
      int idx = t + 256 * r;
      int cc = idx >> 6, o4 = (idx & 63) << 2;
      *(float4*)(Wt + cc * 256 + o4) =
          *(const float4*)(w_eT + (ct + cc) * 256 + o4);
    }
    __syncthreads();
#pragma unroll
    for (int kk = 0; kk < 16; ++kk) {
      float e[4], wv[4][4];
      *(float4*)e = *(const float4*)(Et + kk * 64 + tx * 4);
#pragma unroll
      for (int g = 0; g < 4; ++g)
        *(float4*)wv[g] = *(const float4*)(Wt + kk * 256 + ty * 4 + 64 * g);
#pragma unroll
      for (int g = 0; g < 4; ++g)
#pragma unroll
        for (int oo = 0; oo < 4; ++oo)
#pragma unroll
          for (int p = 0; p < 4; ++p)
            acc[g * 4 + oo][p] = fmaf(wv[g][oo], e[p], acc[g * 4 + oo][p]);
    }
  }
  const float* xb = x + (size_t)b * 256 * HW_ + px0;
  float* ob = out + (size_t)b * 256 * HW_ + px0;
#pragma unroll
  for (int g = 0; g < 4; ++g)
#pragma unroll
    for (int oo = 0; oo < 4; ++oo) {
      int o = ty * 4 + 64 * g + oo;
      float4 xv = *(const float4*)(xb + (size_t)o * HW_ + tx * 4);
      float4 rv;
      rv.x = acc[g * 4 + oo][0] + xv.x;
      rv.y = acc[g * 4 + oo][1] + xv.y;
      rv.z = acc[g * 4 + oo][2] + xv.z;
      rv.w = acc[g * 4 + oo][3] + xv.w;
      *(float4*)(ob + (size_t)o * HW_ + tx * 4) = rv;
    }
}

// ---------------------------------------------------------------------------
extern "C" void kernel_launch(void* const* d_in, const int* in_sizes, int n_in,
                              void* d_out, int out_size, void* d_ws, size_t ws_size,
                              hipStream_t stream) {
  const float* x    = (const float*)d_in[0];
  const float* w1   = (const float*)d_in[1];
  const float* w3   = (const float*)d_in[2];
  const float* w5   = (const float*)d_in[3];
  const float* w7   = (const float*)d_in[4];
  const float* w_ab = (const float*)d_in[5];
  const float* w_fc = (const float*)d_in[6];
  const float* w_fd = (const float*)d_in[7];
  const float* w_e  = (const float*)d_in[8];
  float* out = (float*)d_out;

  float* ws  = (float*)d_ws;          // needs 3,686,400 floats = 14.75 MB
  float* avg = ws;                    // 409600 (reused as w_eT after k_convs)
  float* mx  = ws + 409600;           // 409600
  float* bm  = ws + 819200;           // 409600
  float* Fb  = ws + 1228800;          // 1638400 (B,4,H,W)
  float* cm  = ws + 2867200;          // 409600
  float* Sm  = ws + 3276800;          // 409600 (B,160,160)
  float* weT = avg;                   // 65536, avg is dead after k_convs

  k_reduce<<<NPIX_ / 4 / 64, 64, 0, stream>>>(x, w_ab, avg, mx, bm);
  k_convs<<<dim3(10, 10, 16), 256, 0, stream>>>(avg, mx, w1, w3, w5, w7, w_fc, Fb, cm);
  k_wt<<<256, 256, 0, stream>>>(w_e, weT);
  k_attn<<<dim3(160, 16), 256, 0, stream>>>(bm, cm, Sm);
  k_smm<<<dim3(256, 16), 256, 0, stream>>>(Sm, Fb, w_fd, out);
  k_emm<<<dim3(400, 16), 256, 0, stream>>>(weT, x, out);
}